// Round 3
// baseline (183.718 us; speedup 1.0000x reference)
//
#include <hip/hip_runtime.h>

// Problem constants (fixed by setup_inputs): B=4,T=32,H=224,W=224,C=3
namespace {
constexpr int B_ = 4, T_ = 32, H_ = 224, W_ = 224;
constexpr int HW_ = H_ * W_;              // 50176
constexpr int NPIX_ = B_ * T_ * HW_;      // 6422528
constexpr int N1_ = 79;                   // int(6422528*0.2*0.8 // 13005)
constexpr int N2_ = 9;                    // int(6422528*0.2*0.1 // 13005)
constexpr int NBOX_RW_ = N1_ + N2_;       // 88 boxes affect pixel output
constexpr int NBOX_M_  = N1_ + 2 * N2_;   // 97 boxes affect M
constexpr int HALF_T = 2, HALF_HW = 25;
constexpr int GPT_ = 16;                  // pixels per group (224 % 16 == 0)
constexpr int GPR_ = W_ / GPT_;           // 14 groups per row
constexpr int GPS_ = H_ * GPR_;           // 3136 groups per slice
constexpr int NGRP_ = B_ * T_ * GPS_;     // 401408 groups total
}

// One block per (b,t) slice. Stages the applicable rects in LDS (order
// irrelevant: R2 always wins over R1, values within a class identical),
// then emits one u32 mask per 16-pixel group: m1 bits 0..15, m2 bits 16..31.
// Also writes the per-slice M flag and gathers random_token.
__global__ __launch_bounds__(256) void build_masks(
    const float* __restrict__ frames,
    const int* __restrict__ bb, const int* __restrict__ tt,
    const int* __restrict__ hh, const int* __restrict__ ww,
    const int* __restrict__ rb, const int* __restrict__ rt,
    const int* __restrict__ rh, const int* __restrict__ rw,
    unsigned* __restrict__ gmask, float* __restrict__ rtok,
    float* __restrict__ Mout)
{
    __shared__ int4 r1[NBOX_RW_];
    __shared__ int4 r2[N2_];
    __shared__ int c1, c2, c3;
    const int s = blockIdx.x;
    const int tid = threadIdx.x;
    if (tid == 0) { c1 = 0; c2 = 0; c3 = 0; }
    __syncthreads();

    if (s == 0 && tid == 0) {
        long idx = (((long)rb[0] * T_ + rt[0]) * H_ + rh[0]) * W_ + rw[0];
        rtok[0] = frames[idx * 3 + 0];
        rtok[1] = frames[idx * 3 + 1];
        rtok[2] = frames[idx * 3 + 2];
    }

    const int sb = s / T_, st = s % T_;
    if (tid < NBOX_M_) {
        const int i = tid;
        int tlo = max(tt[i] - HALF_T, 0);
        int thi = min(tt[i] + HALF_T, T_ - 1);   // exclusive (ref uses size-1)
        if (bb[i] == sb && st >= tlo && st < thi) {
            if (i >= NBOX_RW_) {
                atomicAdd(&c3, 1);               // R3: M only
            } else {
                int4 r;
                r.x = max(hh[i] - HALF_HW, 0);
                r.y = min(hh[i] + HALF_HW, H_ - 1);   // exclusive
                r.z = max(ww[i] - HALF_HW, 0);
                r.w = min(ww[i] + HALF_HW, W_ - 1);   // exclusive
                if (i < N1_) r1[atomicAdd(&c1, 1)] = r;
                else         r2[atomicAdd(&c2, 1)] = r;
            }
        }
    }
    __syncthreads();

    if (tid == 0) Mout[s] = (c1 + c2 + c3) > 0 ? 1.0f : 0.0f;

    const int n1 = c1, n2 = c2;
    for (int g = tid; g < GPS_; g += 256) {
        int h  = g / GPR_;
        int w0 = (g - h * GPR_) * GPT_;
        unsigned m1 = 0, m2 = 0;
        for (int j = 0; j < n1; ++j) {
            int4 r = r1[j];
            if (h >= r.x && h < r.y) {
                int lo = max(r.z - w0, 0), hi = min(r.w - w0, GPT_);
                if (hi > lo) m1 |= ((1u << (hi - lo)) - 1u) << lo;
            }
        }
        for (int j = 0; j < n2; ++j) {
            int4 r = r2[j];
            if (h >= r.x && h < r.y) {
                int lo = max(r.z - w0, 0), hi = min(r.w - w0, GPT_);
                if (hi > lo) m2 |= ((1u << (hi - lo)) - 1u) << lo;
            }
        }
        gmask[s * GPS_ + g] = m1 | (m2 << 16);
    }
}

// Hot kernel: one thread per 16 pixels (48 floats = 12x float4). All loads
// are independent (mask word first, then the 12 frame loads) — no dependent
// loop bounds, no division: group index == gid.
__global__ __launch_bounds__(256, 4) void apply_mask(
    const float* __restrict__ frames, const float* __restrict__ mtok,
    const unsigned* __restrict__ gmask, const float* __restrict__ rtok,
    float* __restrict__ out)
{
    const int gid = blockIdx.x * 256 + threadIdx.x;   // grid covers NGRP_ exactly
    const unsigned mw = gmask[gid];

    const float4* fin = (const float4*)(frames + (long)gid * (GPT_ * 3));
    float4 f[12];
#pragma unroll
    for (int k = 0; k < 12; ++k) f[k] = fin[k];

    if (mw) {
        float mt0 = mtok[0], mt1 = mtok[1], mt2 = mtok[2];
        float rt0 = rtok[0], rt1 = rtok[1], rt2 = rtok[2];
        unsigned m1 = mw & 0xFFFFu, m2 = mw >> 16;
        float* v = (float*)f;
#pragma unroll
        for (int k = 0; k < GPT_; ++k) {
            bool b2 = (m2 >> k) & 1u, b1 = (m1 >> k) & 1u;
            v[k * 3 + 0] = b2 ? rt0 : (b1 ? mt0 : v[k * 3 + 0]);
            v[k * 3 + 1] = b2 ? rt1 : (b1 ? mt1 : v[k * 3 + 1]);
            v[k * 3 + 2] = b2 ? rt2 : (b1 ? mt2 : v[k * 3 + 2]);
        }
    }

    float4* fo = (float4*)(out + (long)gid * (GPT_ * 3));
#pragma unroll
    for (int k = 0; k < 12; ++k) fo[k] = f[k];
}

extern "C" void kernel_launch(void* const* d_in, const int* in_sizes, int n_in,
                              void* d_out, int out_size, void* d_ws, size_t ws_size,
                              hipStream_t stream)
{
    const float* frames = (const float*)d_in[0];
    const float* mtok   = (const float*)d_in[1];
    const int* b  = (const int*)d_in[2];
    const int* t  = (const int*)d_in[3];
    const int* h  = (const int*)d_in[4];
    const int* w  = (const int*)d_in[5];
    const int* rb = (const int*)d_in[6];
    const int* rt = (const int*)d_in[7];
    const int* rh = (const int*)d_in[8];
    const int* rw = (const int*)d_in[9];

    // ws layout: gmask u32[401408] (1.57 MB) | rtok f32[3]
    unsigned* gmask = (unsigned*)d_ws;
    float*    rtok  = (float*)((char*)d_ws + (size_t)NGRP_ * 4);

    float* out_frames = (float*)d_out;
    float* out_M      = out_frames + (long)NPIX_ * 3;   // (B,T) flags as floats

    build_masks<<<B_ * T_, 256, 0, stream>>>(frames, b, t, h, w, rb, rt, rh, rw,
                                             gmask, rtok, out_M);

    apply_mask<<<NGRP_ / 256, 256, 0, stream>>>(frames, mtok, gmask, rtok,
                                                out_frames);
}

// Round 4
// 170.515 us; speedup vs baseline: 1.0774x; 1.0774x over previous
//
#include <hip/hip_runtime.h>

// Problem constants (fixed by setup_inputs): B=4,T=32,H=224,W=224,C=3
namespace {
constexpr int B_ = 4, T_ = 32, H_ = 224, W_ = 224;
constexpr int HW_ = H_ * W_;              // 50176
constexpr int NPIX_ = B_ * T_ * HW_;      // 6422528
constexpr int N1_ = 79;                   // int(6422528*0.2*0.8 // 13005)
constexpr int N2_ = 9;                    // int(6422528*0.2*0.1 // 13005)
constexpr int NBOX_RW_ = N1_ + N2_;       // 88 boxes affect pixel output
constexpr int NBOX_M_  = N1_ + 2 * N2_;   // 97 boxes affect M
constexpr int HALF_T = 2, HALF_HW = 25;
constexpr int GPT_ = 16;                  // pixels per mask word
constexpr int GPR_ = W_ / GPT_;           // 14 words per row
constexpr int GPS_ = H_ * GPR_;           // 3136 words per slice
constexpr int NGRP_ = B_ * T_ * GPS_;     // 401408 words total
// apply_mask tiling: block tile = 1536 float4 = 6144 floats = 2048 pixels
constexpr int F4_TOTAL_ = NPIX_ * 3 / 4;  // 4816896
constexpr int TILE_F4_ = 1536;
constexpr int TILE_PX_ = 2048;
constexpr int TILE_W_  = TILE_PX_ / GPT_; // 128 mask words per tile
constexpr int NBLK_ = F4_TOTAL_ / TILE_F4_; // 3136 exactly
}

// One block per (b,t) slice. Stages the applicable rects in LDS (order
// irrelevant: R2 always wins over R1, values within a class identical),
// then emits one u32 mask per 16-pixel group: m1 bits 0..15, m2 bits 16..31.
// Also writes the per-slice M flags and gathers random_token.
__global__ __launch_bounds__(256) void build_masks(
    const float* __restrict__ frames,
    const int* __restrict__ bb, const int* __restrict__ tt,
    const int* __restrict__ hh, const int* __restrict__ ww,
    const int* __restrict__ rb, const int* __restrict__ rt,
    const int* __restrict__ rh, const int* __restrict__ rw,
    unsigned* __restrict__ gmask, float* __restrict__ rtok,
    float* __restrict__ Mout)
{
    __shared__ int4 r1[NBOX_RW_];
    __shared__ int4 r2[N2_];
    __shared__ int c1, c2, c3;
    const int s = blockIdx.x;
    const int tid = threadIdx.x;
    if (tid == 0) { c1 = 0; c2 = 0; c3 = 0; }
    __syncthreads();

    if (s == 0 && tid == 0) {
        long idx = (((long)rb[0] * T_ + rt[0]) * H_ + rh[0]) * W_ + rw[0];
        rtok[0] = frames[idx * 3 + 0];
        rtok[1] = frames[idx * 3 + 1];
        rtok[2] = frames[idx * 3 + 2];
    }

    const int sb = s / T_, st = s % T_;
    if (tid < NBOX_M_) {
        const int i = tid;
        int tlo = max(tt[i] - HALF_T, 0);
        int thi = min(tt[i] + HALF_T, T_ - 1);   // exclusive (ref uses size-1)
        if (bb[i] == sb && st >= tlo && st < thi) {
            if (i >= NBOX_RW_) {
                atomicAdd(&c3, 1);               // R3: M only
            } else {
                int4 r;
                r.x = max(hh[i] - HALF_HW, 0);
                r.y = min(hh[i] + HALF_HW, H_ - 1);   // exclusive
                r.z = max(ww[i] - HALF_HW, 0);
                r.w = min(ww[i] + HALF_HW, W_ - 1);   // exclusive
                if (i < N1_) r1[atomicAdd(&c1, 1)] = r;
                else         r2[atomicAdd(&c2, 1)] = r;
            }
        }
    }
    __syncthreads();

    if (tid == 0) Mout[s] = (c1 + c2 + c3) > 0 ? 1.0f : 0.0f;

    const int n1 = c1, n2 = c2;
    for (int g = tid; g < GPS_; g += 256) {
        int h  = g / GPR_;
        int w0 = (g - h * GPR_) * GPT_;
        unsigned m1 = 0, m2 = 0;
        for (int j = 0; j < n1; ++j) {
            int4 r = r1[j];
            if (h >= r.x && h < r.y) {
                int lo = max(r.z - w0, 0), hi = min(r.w - w0, GPT_);
                if (hi > lo) m1 |= ((1u << (hi - lo)) - 1u) << lo;
            }
        }
        for (int j = 0; j < n2; ++j) {
            int4 r = r2[j];
            if (h >= r.x && h < r.y) {
                int lo = max(r.z - w0, 0), hi = min(r.w - w0, GPT_);
                if (hi > lo) m2 |= ((1u << (hi - lo)) - 1u) << lo;
            }
        }
        gmask[s * GPS_ + g] = m1 | (m2 << 16);
    }
}

// Hot kernel. Block tile = 1536 contiguous float4 (= 2048 pixels, pixel
// aligned). Thread t touches float4s tileBase + t + 256k — every memory
// instruction is lane-contiguous (lane i at +16B*i => 1 transaction/instr).
// Mask words for the tile live in LDS; block-level __syncthreads_or gives a
// pure-copy fast path for unmasked tiles.
__global__ __launch_bounds__(256) void apply_mask(
    const float4* __restrict__ frames4, const float* __restrict__ mtok,
    const unsigned* __restrict__ gmask, const float* __restrict__ rtok,
    float4* __restrict__ out4)
{
    __shared__ unsigned smask[TILE_W_];
    __shared__ float stok[6];               // {mt0,mt1,mt2,rt0,rt1,rt2}
    const int tid = threadIdx.x;
    const int blk = blockIdx.x;

    unsigned wv = 0;
    if (tid < TILE_W_) { wv = gmask[blk * TILE_W_ + tid]; smask[tid] = wv; }
    if (tid == 0) {
        stok[0] = mtok[0]; stok[1] = mtok[1]; stok[2] = mtok[2];
        stok[3] = rtok[0]; stok[4] = rtok[1]; stok[5] = rtok[2];
    }

    const long ebase = (long)blk * TILE_F4_;
    float4 f[6];
#pragma unroll
    for (int k = 0; k < 6; ++k) f[k] = frames4[ebase + tid + k * 256];

    const int any = __syncthreads_or(int(wv != 0));

    if (any) {
#pragma unroll
        for (int k = 0; k < 6; ++k) {
            const int el = tid + k * 256;      // local float4 index in tile
            const int pl = (4 * el) / 3;       // first local pixel covered
            const unsigned wa = smask[pl >> 4];
            const unsigned wb = smask[(pl + 1) >> 4];   // pl+1 <= 2047, safe
            if (wa | wb) {
                float* v = (float*)&f[k];
#pragma unroll
                for (int j = 0; j < 4; ++j) {
                    int fi = 4 * el + j;       // local float index
                    int q  = fi / 3;           // local pixel
                    int c  = fi - 3 * q;       // component 0..2
                    unsigned w = smask[q >> 4];
                    int bpos = q & 15;
                    if ((w >> (bpos + 16)) & 1u)      v[j] = stok[3 + c];
                    else if ((w >> bpos) & 1u)        v[j] = stok[c];
                }
            }
        }
    }

#pragma unroll
    for (int k = 0; k < 6; ++k) out4[ebase + tid + k * 256] = f[k];
}

extern "C" void kernel_launch(void* const* d_in, const int* in_sizes, int n_in,
                              void* d_out, int out_size, void* d_ws, size_t ws_size,
                              hipStream_t stream)
{
    const float* frames = (const float*)d_in[0];
    const float* mtok   = (const float*)d_in[1];
    const int* b  = (const int*)d_in[2];
    const int* t  = (const int*)d_in[3];
    const int* h  = (const int*)d_in[4];
    const int* w  = (const int*)d_in[5];
    const int* rb = (const int*)d_in[6];
    const int* rt = (const int*)d_in[7];
    const int* rh = (const int*)d_in[8];
    const int* rw = (const int*)d_in[9];

    // ws layout: gmask u32[401408] (1.57 MB) | rtok f32[3]
    unsigned* gmask = (unsigned*)d_ws;
    float*    rtok  = (float*)((char*)d_ws + (size_t)NGRP_ * 4);

    float* out_frames = (float*)d_out;
    float* out_M      = out_frames + (long)NPIX_ * 3;   // (B,T) flags as floats

    build_masks<<<B_ * T_, 256, 0, stream>>>(frames, b, t, h, w, rb, rt, rh, rw,
                                             gmask, rtok, out_M);

    apply_mask<<<NBLK_, 256, 0, stream>>>((const float4*)frames, mtok, gmask,
                                          rtok, (float4*)out_frames);
}

// Round 6
// 167.793 us; speedup vs baseline: 1.0949x; 1.0162x over previous
//
#include <hip/hip_runtime.h>

// Problem constants (fixed by setup_inputs): B=4,T=32,H=224,W=224,C=3
namespace {
constexpr int B_ = 4, T_ = 32, H_ = 224, W_ = 224;
constexpr int HW_ = H_ * W_;              // 50176
constexpr int NPIX_ = B_ * T_ * HW_;      // 6422528
constexpr int N1_ = 79;                   // int(6422528*0.2*0.8 // 13005)
constexpr int N2_ = 9;                    // int(6422528*0.2*0.1 // 13005)
constexpr int NBOX_RW_ = N1_ + N2_;       // 88 boxes affect pixel output
constexpr int NBOX_M_  = N1_ + 2 * N2_;   // 97 boxes affect M
constexpr int HALF_T = 2, HALF_HW = 25;
constexpr int GPT_ = 16;                  // pixels per mask word
constexpr int GPR_ = W_ / GPT_;           // 14 words per row
constexpr int GPS_ = H_ * GPR_;           // 3136 words per slice
constexpr int NGRP_ = B_ * T_ * GPS_;     // 401408 words total
// apply_mask grid-stride: F4_TOTAL_ = 2^15*147; stride divisible by 3 and
// dividing F4_TOTAL_ exactly -> no bounds check, constant per-thread phase.
constexpr int F4_TOTAL_ = NPIX_ * 3 / 4;  // 4816896
constexpr int ABLK_ = 2352;
constexpr unsigned STRIDE_ = ABLK_ * 256; // 602112, %3==0
constexpr int NITER_ = F4_TOTAL_ / (int)STRIDE_;  // 8, exact
}

typedef float floatx4 __attribute__((ext_vector_type(4)));   // native vec for nt-store

// One block per (b,t) slice. Stages applicable rects in LDS (order
// irrelevant: R2 always wins over R1, values within a class identical),
// then emits one u32 mask per 16-pixel group: m1 bits 0..15, m2 bits 16..31.
// Also writes per-slice M flags and gathers random_token.
__global__ __launch_bounds__(256) void build_masks(
    const float* __restrict__ frames,
    const int* __restrict__ bb, const int* __restrict__ tt,
    const int* __restrict__ hh, const int* __restrict__ ww,
    const int* __restrict__ rb, const int* __restrict__ rt,
    const int* __restrict__ rh, const int* __restrict__ rw,
    unsigned* __restrict__ gmask, float* __restrict__ rtok,
    float* __restrict__ Mout)
{
    __shared__ int4 r1[NBOX_RW_];
    __shared__ int4 r2[N2_];
    __shared__ int c1, c2, c3;
    const int s = blockIdx.x;
    const int tid = threadIdx.x;
    if (tid == 0) { c1 = 0; c2 = 0; c3 = 0; }
    __syncthreads();

    if (s == 0 && tid == 0) {
        long idx = (((long)rb[0] * T_ + rt[0]) * H_ + rh[0]) * W_ + rw[0];
        rtok[0] = frames[idx * 3 + 0];
        rtok[1] = frames[idx * 3 + 1];
        rtok[2] = frames[idx * 3 + 2];
    }

    const int sb = s / T_, st = s % T_;
    if (tid < NBOX_M_) {
        const int i = tid;
        int tlo = max(tt[i] - HALF_T, 0);
        int thi = min(tt[i] + HALF_T, T_ - 1);   // exclusive (ref uses size-1)
        if (bb[i] == sb && st >= tlo && st < thi) {
            if (i >= NBOX_RW_) {
                atomicAdd(&c3, 1);               // R3: M only
            } else {
                int4 r;
                r.x = max(hh[i] - HALF_HW, 0);
                r.y = min(hh[i] + HALF_HW, H_ - 1);   // exclusive
                r.z = max(ww[i] - HALF_HW, 0);
                r.w = min(ww[i] + HALF_HW, W_ - 1);   // exclusive
                if (i < N1_) r1[atomicAdd(&c1, 1)] = r;
                else         r2[atomicAdd(&c2, 1)] = r;
            }
        }
    }
    __syncthreads();

    if (tid == 0) Mout[s] = (c1 + c2 + c3) > 0 ? 1.0f : 0.0f;

    const int n1 = c1, n2 = c2;
    for (int g = tid; g < GPS_; g += 256) {
        int h  = g / GPR_;
        int w0 = (g - h * GPR_) * GPT_;
        unsigned m1 = 0, m2 = 0;
        for (int j = 0; j < n1; ++j) {
            int4 r = r1[j];
            if (h >= r.x && h < r.y) {
                int lo = max(r.z - w0, 0), hi = min(r.w - w0, GPT_);
                if (hi > lo) m1 |= ((1u << (hi - lo)) - 1u) << lo;
            }
        }
        for (int j = 0; j < n2; ++j) {
            int4 r = r2[j];
            if (h >= r.x && h < r.y) {
                int lo = max(r.z - w0, 0), hi = min(r.w - w0, GPT_);
                if (hi > lo) m2 |= ((1u << (hi - lo)) - 1u) << lo;
            }
        }
        gmask[s * GPS_ + g] = m1 | (m2 << 16);
    }
}

// Hot kernel: grid-stride float4 copy clone of the 6.3 TB/s probe structure.
// 8 fully independent iterations per thread (unrolled), no LDS, no barrier.
// Stride % 3 == 0 => each thread's float4<->pixel phase is constant: token
// vectors pre-rotated once; per-iter mask lookup is 2 u32 loads (L1-hot)
// + ~6 int ops (exact /3 via inverse mod 2^32).
__global__ __launch_bounds__(256) void apply_mask(
    const floatx4* __restrict__ frames4, const float* __restrict__ mtok,
    const unsigned* __restrict__ gmask, const float* __restrict__ rtok,
    floatx4* __restrict__ out4)
{
    const unsigned tid0 = blockIdx.x * 256u + threadIdx.x;
    const unsigned ph = tid0 % 3u;          // phase: float j has comp (ph+j)%3

    float m0 = mtok[0], m1 = mtok[1], m2 = mtok[2];
    float r0 = rtok[0], r1 = rtok[1], r2 = rtok[2];
    // rotated tokens: slot j holds token component (ph+j)%3 (slot 3 == slot 0)
    float a0 = ph == 0 ? m0 : (ph == 1 ? m1 : m2);
    float a1 = ph == 0 ? m1 : (ph == 1 ? m2 : m0);
    float a2 = ph == 0 ? m2 : (ph == 1 ? m0 : m1);
    float b0 = ph == 0 ? r0 : (ph == 1 ? r1 : r2);
    float b1 = ph == 0 ? r1 : (ph == 1 ? r2 : r0);
    float b2 = ph == 0 ? r2 : (ph == 1 ? r0 : r1);
    // pixel offsets of floats j=1,2 relative to first pixel m (j=0 -> 0, j=3 -> 1)
    const unsigned d1 = (ph + 1) / 3, d2 = (ph + 2) / 3;

#pragma unroll
    for (int it = 0; it < NITER_; ++it) {
        const unsigned g4 = tid0 + (unsigned)it * STRIDE_;
        const unsigned m = (4u * g4 - ph) * 0xAAAAAAABu;  // (4*g4-ph)/3 exact
        const unsigned w0i = m >> 4;
        const unsigned wa = gmask[w0i];
        const unsigned wb = gmask[(m + 1u) >> 4];
        floatx4 v = frames4[g4];
        if (wa | wb) {
            unsigned p1 = m + d1, p2 = m + d2, p3 = m + 1u;
            unsigned w1 = ((p1 >> 4) == w0i) ? wa : wb;
            unsigned w2 = ((p2 >> 4) == w0i) ? wa : wb;
            unsigned w3 = ((p3 >> 4) == w0i) ? wa : wb;
            unsigned q0 = m & 15u, q1 = p1 & 15u, q2 = p2 & 15u, q3 = p3 & 15u;
            v.x = ((wa >> (q0 + 16)) & 1u) ? b0 : (((wa >> q0) & 1u) ? a0 : v.x);
            v.y = ((w1 >> (q1 + 16)) & 1u) ? b1 : (((w1 >> q1) & 1u) ? a1 : v.y);
            v.z = ((w2 >> (q2 + 16)) & 1u) ? b2 : (((w2 >> q2) & 1u) ? a2 : v.z);
            v.w = ((w3 >> (q3 + 16)) & 1u) ? b0 : (((w3 >> q3) & 1u) ? a0 : v.w);
        }
        __builtin_nontemporal_store(v, &out4[g4]);
    }
}

extern "C" void kernel_launch(void* const* d_in, const int* in_sizes, int n_in,
                              void* d_out, int out_size, void* d_ws, size_t ws_size,
                              hipStream_t stream)
{
    const float* frames = (const float*)d_in[0];
    const float* mtok   = (const float*)d_in[1];
    const int* b  = (const int*)d_in[2];
    const int* t  = (const int*)d_in[3];
    const int* h  = (const int*)d_in[4];
    const int* w  = (const int*)d_in[5];
    const int* rb = (const int*)d_in[6];
    const int* rt = (const int*)d_in[7];
    const int* rh = (const int*)d_in[8];
    const int* rw = (const int*)d_in[9];

    // ws layout: gmask u32[401408] (1.57 MB) | rtok f32[3]
    unsigned* gmask = (unsigned*)d_ws;
    float*    rtok  = (float*)((char*)d_ws + (size_t)NGRP_ * 4);

    float* out_frames = (float*)d_out;
    float* out_M      = out_frames + (long)NPIX_ * 3;   // (B,T) flags as floats

    build_masks<<<B_ * T_, 256, 0, stream>>>(frames, b, t, h, w, rb, rt, rh, rw,
                                             gmask, rtok, out_M);

    apply_mask<<<ABLK_, 256, 0, stream>>>((const floatx4*)frames, mtok, gmask,
                                          rtok, (floatx4*)out_frames);
}